// Round 8
// baseline (114.325 us; speedup 1.0000x reference)
//
#include <hip/hip_runtime.h>

constexpr int kB    = 8;
constexpr int kN    = 512;
constexpr int kFIN  = 256;
constexpr int kFOUT = 128;
constexpr int kNE   = 10;
constexpr int kBN   = kB * kN;
constexpr float kALPHA = 0.2f;
constexpr float kNEG   = -9e15f;

// ---------------------------------------------------------------------------
// Kernel 1: typed projection + s1/s2 + emb.a2 table.
// Grid 512 x 256 threads, 8 rows/block.
// Thread = (o-pair o0 = (tid&63)*2, kq = tid>>6 -> 64-wide k-quarter).
// Each thread: 3 types x 8 rows x 2 outs (48 acc regs) over 64 k.
// Per 4-k chunk: 8 ds_read_b128 (x broadcast) + 12 global dwordx2 (W)
// + 192 FMA -> 24 FMA per LDS instr (2x round-7 ratio; LDS-pipe was the
// bottleneck: 1 LDS pipe per CU vs 4 FMA SIMDs).
// Quarters combined via 36 KB LDS (one slot per kq>0), 1 sync.
// ---------------------------------------------------------------------------
__global__ __launch_bounds__(256) void proj_kernel(
    const float* __restrict__ node_rep,  // (B*N, FIN)
    const float* __restrict__ mask,      // (T, B*N)
    const float* __restrict__ W,         // (T, FIN, FOUT)
    const float* __restrict__ bias,      // (T, FOUT)
    const float* __restrict__ a1,
    const float* __restrict__ a2,
    const float* __restrict__ a_b,
    const float* __restrict__ emb,       // (NE+1, FOUT)
    float* __restrict__ h,               // (B*N, FOUT)
    float* __restrict__ s1,              // (B*N) a_b folded
    float* __restrict__ s2,              // (B*N)
    float* __restrict__ emb_a2)          // (16)
{
    __shared__ float xs[8][kFIN];             //  8 KB
    __shared__ float parts[3][3][8][kFOUT];   // 36 KB [kq-1][t][r][o]

    const int tid  = threadIdx.x;
    const int row0 = blockIdx.x * 8;
    const int o0   = (tid & 63) * 2;
    const int kq   = tid >> 6;               // 0..3 (== wave id)

    #pragma unroll
    for (int it = 0; it < 2; ++it) {         // 512 quads (8 rows x 64)
        const int idx = tid + it * 256;
        const int r = idx >> 6, q = idx & 63;
        *(float4*)&xs[r][q * 4] =
            *(const float4*)&node_rep[(size_t)(row0 + r) * kFIN + q * 4];
    }
    __syncthreads();

    float2 acc[3][8];
    #pragma unroll
    for (int t = 0; t < 3; ++t)
        #pragma unroll
        for (int r = 0; r < 8; ++r) acc[t][r] = {0.f, 0.f};

    const float* Wo = W + o0;
    const int k0 = kq * 64;

    #pragma unroll 2
    for (int c = 0; c < 16; ++c) {           // 4 k per chunk
        const int kb = k0 + c * 4;
        float2 w[3][4];
        #pragma unroll
        for (int t = 0; t < 3; ++t)
            #pragma unroll
            for (int cc = 0; cc < 4; ++cc)
                w[t][cc] = *(const float2*)&Wo[(size_t)(t * kFIN + kb + cc) * kFOUT];
        float4 xv[8];
        #pragma unroll
        for (int r = 0; r < 8; ++r)          // wave-uniform addr -> broadcast
            xv[r] = *(const float4*)&xs[r][kb];
        #pragma unroll
        for (int cc = 0; cc < 4; ++cc)
            #pragma unroll
            for (int r = 0; r < 8; ++r) {
                const float x = ((const float*)&xv[r])[cc];
                acc[0][r].x = fmaf(w[0][cc].x, x, acc[0][r].x);
                acc[0][r].y = fmaf(w[0][cc].y, x, acc[0][r].y);
                acc[1][r].x = fmaf(w[1][cc].x, x, acc[1][r].x);
                acc[1][r].y = fmaf(w[1][cc].y, x, acc[1][r].y);
                acc[2][r].x = fmaf(w[2][cc].x, x, acc[2][r].x);
                acc[2][r].y = fmaf(w[2][cc].y, x, acc[2][r].y);
            }
    }

    if (kq > 0) {
        #pragma unroll
        for (int t = 0; t < 3; ++t)
            #pragma unroll
            for (int r = 0; r < 8; ++r)
                *(float2*)&parts[kq - 1][t][r][o0] = acc[t][r];  // 2 lanes/bank: free
    }
    __syncthreads();

    if (kq == 0) {
        #pragma unroll
        for (int r = 0; r < 8; ++r) {
            const int row = row0 + r;
            float2 hv = {0.f, 0.f};
            #pragma unroll
            for (int t = 0; t < 3; ++t) {
                float sx = acc[t][r].x, sy = acc[t][r].y;
                #pragma unroll
                for (int s = 0; s < 3; ++s) {
                    sx += parts[s][t][r][o0];
                    sy += parts[s][t][r][o0 + 1];
                }
                const float2 bt = *(const float2*)&bias[t * kFOUT + o0];
                const float  mt = mask[t * kBN + row];
                hv.x = fmaf(mt, sx + bt.x, hv.x);
                hv.y = fmaf(mt, sy + bt.y, hv.y);
            }
            *(float2*)&h[(size_t)row * kFOUT + o0] = hv;
            *(float2*)&parts[0][0][r][o0] = hv;   // stash for s1/s2
        }
    }
    __syncthreads();

    // s1/s2: 4 waves x 2 rows
    {
        const int wv = tid >> 6, lane = tid & 63;
        #pragma unroll
        for (int rr = 0; rr < 2; ++rr) {
            const int r = wv * 2 + rr;
            const float v0 = parts[0][0][r][lane];
            const float v1 = parts[0][0][r][64 + lane];
            float p1 = v0 * a1[lane] + v1 * a1[64 + lane];
            float p2 = v0 * a2[lane] + v1 * a2[64 + lane];
            #pragma unroll
            for (int off = 32; off; off >>= 1) {
                p1 += __shfl_down(p1, off);
                p2 += __shfl_down(p2, off);
            }
            if (lane == 0) {
                s1[row0 + r] = p1 + a_b[0];
                s2[row0 + r] = p2;
            }
        }
    }

    // emb.a2 table once (block 0): 11 rows x 16 lanes
    if (blockIdx.x == 0 && tid < 176) {
        const int e = tid >> 4, l = tid & 15;
        float p = 0.f;
        #pragma unroll
        for (int k8 = 0; k8 < 8; ++k8)
            p += emb[e * kFOUT + l + k8 * 16] * a2[l + k8 * 16];
        #pragma unroll
        for (int off = 8; off; off >>= 1) p += __shfl_xor(p, off);
        if (l == 0) emb_a2[e] = p;
    }
}

// ---------------------------------------------------------------------------
// Kernel 2: scores + softmax + histogram + dense attn@h + ELU.
// (UNCHANGED from round 7 for clean A/B attribution.)
// ---------------------------------------------------------------------------
__global__ __launch_bounds__(256) void attn_kernel(
    const int*   __restrict__ adj,     // (B, N, N)
    const float* __restrict__ emb,     // (NE+1, FOUT)
    const float* __restrict__ h,       // (B*N, FOUT)
    const float* __restrict__ s1,      // (B*N) a_b folded
    const float* __restrict__ s2,      // (B*N)
    const float* __restrict__ emb_a2g, // (16)
    float* __restrict__ out)           // (B*N, FOUT)
{
    __shared__ float sc[8][kN + 4];    // 16.5 KB raw scores
    __shared__ int   adjs[8][kN];      // 16 KB (reused as float parts[4][8][128])
    __shared__ float scT[kN][8];       // 16 KB transposed attn
    __shared__ float wsum[8][16];
    __shared__ float ea2[16];

    const int tid = threadIdx.x;
    const int b   = blockIdx.x >> 6;
    const int i0  = (blockIdx.x & 63) * 8;

    if (tid < 16) ea2[tid] = emb_a2g[tid];
    __syncthreads();

    // Phase A: scores (int4/float4 global, float4/int4 LDS)
    const int*   adjb = adj + ((size_t)(b * kN + i0)) * kN;
    const float* s2b  = s2 + b * kN;
    #pragma unroll
    for (int it = 0; it < 4; ++it) {
        const int idx = tid + it * 256;      // quad index < 1024 (8 rows x 128)
        const int r = idx >> 7, jq = idx & 127;
        const int4   av  = *(const int4*)&adjb[(size_t)r * kN + jq * 4];
        const float4 s2v = *(const float4*)&s2b[jq * 4];
        const float  sr  = s1[b * kN + i0 + r];
        float4 sv; float s;
        s = sr + s2v.x + ea2[av.x]; s = s > 0.f ? s : kALPHA * s; sv.x = av.x > 0 ? s : kNEG;
        s = sr + s2v.y + ea2[av.y]; s = s > 0.f ? s : kALPHA * s; sv.y = av.y > 0 ? s : kNEG;
        s = sr + s2v.z + ea2[av.z]; s = s > 0.f ? s : kALPHA * s; sv.z = av.z > 0 ? s : kNEG;
        s = sr + s2v.w + ea2[av.w]; s = s > 0.f ? s : kALPHA * s; sv.w = av.w > 0 ? s : kNEG;
        *(float4*)&sc[r][jq * 4] = sv;
        *(int4*)&adjs[r][jq * 4] = av;
    }
    __syncthreads();

    // Phase B: softmax + histogram, 4 waves x 2 rows; writes transposed scT
    {
        const int wv = tid >> 6, lane = tid & 63;
        #pragma unroll
        for (int rr = 0; rr < 2; ++rr) {
            const int r = wv * 2 + rr;
            float v[8]; int av[8];
            #pragma unroll
            for (int k = 0; k < 8; ++k) {
                v[k]  = sc[r][lane + k * 64];
                av[k] = adjs[r][lane + k * 64];
            }
            float m = v[0];
            #pragma unroll
            for (int k = 1; k < 8; ++k) m = fmaxf(m, v[k]);
            #pragma unroll
            for (int off = 32; off; off >>= 1) m = fmaxf(m, __shfl_xor(m, off));
            float sum = 0.f;
            #pragma unroll
            for (int k = 0; k < 8; ++k) { v[k] = __expf(v[k] - m); sum += v[k]; }
            #pragma unroll
            for (int off = 32; off; off >>= 1) sum += __shfl_xor(sum, off);
            const float inv = 1.0f / sum;
            #pragma unroll
            for (int k = 0; k < 8; ++k) {
                v[k] *= inv;
                scT[lane + k * 64][r] = v[k];
            }
            #pragma unroll
            for (int e = 1; e <= kNE; ++e) {
                float p = 0.f;
                #pragma unroll
                for (int k = 0; k < 8; ++k) p += (av[k] == e) ? v[k] : 0.f;
                #pragma unroll
                for (int off = 32; off; off >>= 1) p += __shfl_xor(p, off);
                if (lane == 0) wsum[r][e] = p;
            }
        }
    }
    __syncthreads();

    // Phase C: dense attn @ h. thread = (f4l: 32 lanes, rg: 2, js: wave)
    const int f4l = tid & 31;
    const int rg  = (tid >> 5) & 1;
    const int js  = tid >> 6;              // 0..3, 128 j each
    const float* hb  = h + ((size_t)(b * kN + js * 128)) * kFOUT + f4l * 4;
    const float* sct = &scT[js * 128][rg * 4];

    float4 acc0 = {0,0,0,0}, acc1 = {0,0,0,0}, acc2 = {0,0,0,0}, acc3 = {0,0,0,0};
    #pragma unroll 4
    for (int jj = 0; jj < 128; ++jj) {
        const float4 w4 = *(const float4*)&sct[jj * 8];   // LDS b128 broadcast
        const float4 hv = *(const float4*)&hb[(size_t)jj * kFOUT];
        acc0.x = fmaf(w4.x, hv.x, acc0.x); acc0.y = fmaf(w4.x, hv.y, acc0.y);
        acc0.z = fmaf(w4.x, hv.z, acc0.z); acc0.w = fmaf(w4.x, hv.w, acc0.w);
        acc1.x = fmaf(w4.y, hv.x, acc1.x); acc1.y = fmaf(w4.y, hv.y, acc1.y);
        acc1.z = fmaf(w4.y, hv.z, acc1.z); acc1.w = fmaf(w4.y, hv.w, acc1.w);
        acc2.x = fmaf(w4.z, hv.x, acc2.x); acc2.y = fmaf(w4.z, hv.y, acc2.y);
        acc2.z = fmaf(w4.z, hv.z, acc2.z); acc2.w = fmaf(w4.z, hv.w, acc2.w);
        acc3.x = fmaf(w4.w, hv.x, acc3.x); acc3.y = fmaf(w4.w, hv.y, acc3.y);
        acc3.z = fmaf(w4.w, hv.z, acc3.z); acc3.w = fmaf(w4.w, hv.w, acc3.w);
    }
    __syncthreads();                       // adjs dead -> reuse as parts

    float* parts = (float*)adjs;           // [js 4][r 8][f 128]
    {
        const int rbase = rg * 4;
        *(float4*)&parts[((js * 8) + rbase + 0) * kFOUT + f4l * 4] = acc0;
        *(float4*)&parts[((js * 8) + rbase + 1) * kFOUT + f4l * 4] = acc1;
        *(float4*)&parts[((js * 8) + rbase + 2) * kFOUT + f4l * 4] = acc2;
        *(float4*)&parts[((js * 8) + rbase + 3) * kFOUT + f4l * 4] = acc3;
    }
    __syncthreads();

    // Reduction + emb correction + ELU + store: thread = (r = tid>>5, 4 f)
    {
        const int r  = tid >> 5;
        const int fl = (tid & 31) * 4;
        float4 a = {0,0,0,0};
        #pragma unroll
        for (int p = 0; p < 4; ++p) {
            const float4 pv = *(const float4*)&parts[((p * 8) + r) * kFOUT + fl];
            a.x += pv.x; a.y += pv.y; a.z += pv.z; a.w += pv.w;
        }
        #pragma unroll
        for (int e = 1; e <= kNE; ++e) {
            const float  wv = wsum[r][e];
            const float4 ev = *(const float4*)&emb[e * kFOUT + fl];
            a.x = fmaf(wv, ev.x, a.x); a.y = fmaf(wv, ev.y, a.y);
            a.z = fmaf(wv, ev.z, a.z); a.w = fmaf(wv, ev.w, a.w);
        }
        a.x = a.x > 0.f ? a.x : expm1f(a.x);
        a.y = a.y > 0.f ? a.y : expm1f(a.y);
        a.z = a.z > 0.f ? a.z : expm1f(a.z);
        a.w = a.w > 0.f ? a.w : expm1f(a.w);
        *(float4*)&out[((size_t)(b * kN + i0 + r)) * kFOUT + fl] = a;
    }
}

// ---------------------------------------------------------------------------
extern "C" void kernel_launch(void* const* d_in, const int* in_sizes, int n_in,
                              void* d_out, int out_size, void* d_ws, size_t ws_size,
                              hipStream_t stream) {
    const float* node_rep = (const float*)d_in[0];
    const float* mask     = (const float*)d_in[1];
    const int*   adj      = (const int*)  d_in[2];
    const float* W        = (const float*)d_in[3];
    const float* bias     = (const float*)d_in[4];
    const float* a1       = (const float*)d_in[5];
    const float* a2       = (const float*)d_in[6];
    const float* a_b      = (const float*)d_in[7];
    const float* emb      = (const float*)d_in[8];
    float* out = (float*)d_out;

    float* ws     = (float*)d_ws;
    float* h      = ws;                            // B*N*FOUT (2 MB)
    float* s1     = h + (size_t)kBN * kFOUT;       // B*N
    float* s2     = s1 + kBN;                      // B*N
    float* emb_a2 = s2 + kBN;                      // 16

    proj_kernel<<<kBN / 8, 256, 0, stream>>>(
        node_rep, mask, W, bias, a1, a2, a_b, emb, h, s1, s2, emb_a2);
    attn_kernel<<<kBN / 8, 256, 0, stream>>>(
        adj, emb, h, s1, s2, emb_a2, out);
}

// Round 9
// 111.561 us; speedup vs baseline: 1.0248x; 1.0248x over previous
//
#include <hip/hip_runtime.h>

constexpr int kB    = 8;
constexpr int kN    = 512;
constexpr int kFIN  = 256;
constexpr int kFOUT = 128;
constexpr int kNE   = 10;
constexpr int kBN   = kB * kN;
constexpr float kALPHA = 0.2f;
constexpr float kNEG   = -9e15f;

// ---------------------------------------------------------------------------
// Kernel 1a: typed projection, k-split across blocks for occupancy.
// Grid 2048 = 512 row-octets x 4 k-slices (64 k each). 128 threads =
// (o0 = (tid&63)*2 -> one wave spans all 128 outs, kh = tid>>6 -> 32-k half).
// Each thread: 3 t x 8 rows x 2 outs (48 acc) over 32 k.
// Per 4-k chunk: 12 global dwordx2 (W, read ONCE per block - no wave
// redundancy) + 8 ds_read_b128 (x broadcast) + 192 FMA.
// kh-halves combined via 12 KB LDS; mask applied in-block; partial -> ws.
// 14 KB LDS, ~120 VGPR -> ~8 blocks/CU = 16 waves/CU (4x round-8 occupancy).
// ---------------------------------------------------------------------------
__global__ __launch_bounds__(128) void proj_kernel(
    const float* __restrict__ node_rep,  // (B*N, FIN)
    const float* __restrict__ mask,      // (T, B*N)
    const float* __restrict__ W,         // (T, FIN, FOUT)
    float* __restrict__ part)            // (4, B*N, FOUT) k-slice partials
{
    __shared__ float xs[8][64];            // 2 KB
    __shared__ float pcomb[3][8][kFOUT];   // 12 KB

    const int tid  = threadIdx.x;
    const int rb   = blockIdx.x >> 2;
    const int sl   = blockIdx.x & 3;
    const int row0 = rb * 8;
    const int k0   = sl * 64;

    {   // stage x tile: 8 rows x 64 k = 128 float4, one per thread
        const int r = tid >> 4, q = tid & 15;
        *(float4*)&xs[r][q * 4] =
            *(const float4*)&node_rep[(size_t)(row0 + r) * kFIN + k0 + q * 4];
    }
    __syncthreads();

    const int o0 = (tid & 63) * 2;
    const int kh = tid >> 6;               // 0..1 -> 32-k half

    float2 acc[3][8];
    #pragma unroll
    for (int t = 0; t < 3; ++t)
        #pragma unroll
        for (int r = 0; r < 8; ++r) acc[t][r] = {0.f, 0.f};

    const float* Wo = W + o0;

    #pragma unroll
    for (int c = 0; c < 8; ++c) {          // 8 chunks x 4 k
        const int kb = kh * 32 + c * 4;    // within slice
        float2 w[3][4];
        #pragma unroll
        for (int t = 0; t < 3; ++t)
            #pragma unroll
            for (int cc = 0; cc < 4; ++cc)
                w[t][cc] = *(const float2*)&Wo[(size_t)(t * kFIN + k0 + kb + cc) * kFOUT];
        float4 xv[8];
        #pragma unroll
        for (int r = 0; r < 8; ++r)        // wave-uniform addr -> broadcast
            xv[r] = *(const float4*)&xs[r][kb];
        #pragma unroll
        for (int cc = 0; cc < 4; ++cc)
            #pragma unroll
            for (int r = 0; r < 8; ++r) {
                const float x = ((const float*)&xv[r])[cc];
                acc[0][r].x = fmaf(w[0][cc].x, x, acc[0][r].x);
                acc[0][r].y = fmaf(w[0][cc].y, x, acc[0][r].y);
                acc[1][r].x = fmaf(w[1][cc].x, x, acc[1][r].x);
                acc[1][r].y = fmaf(w[1][cc].y, x, acc[1][r].y);
                acc[2][r].x = fmaf(w[2][cc].x, x, acc[2][r].x);
                acc[2][r].y = fmaf(w[2][cc].y, x, acc[2][r].y);
            }
    }

    if (kh == 1) {
        #pragma unroll
        for (int t = 0; t < 3; ++t)
            #pragma unroll
            for (int r = 0; r < 8; ++r)
                *(float2*)&pcomb[t][r][o0] = acc[t][r];   // 2 lanes/bank: free
    }
    __syncthreads();

    if (kh == 0) {
        #pragma unroll
        for (int r = 0; r < 8; ++r) {
            const int row = row0 + r;
            const float m0 = mask[0 * kBN + row];
            const float m1 = mask[1 * kBN + row];
            const float m2 = mask[2 * kBN + row];
            float2 pv;
            pv.x = m0 * (acc[0][r].x + pcomb[0][r][o0])
                 + m1 * (acc[1][r].x + pcomb[1][r][o0])
                 + m2 * (acc[2][r].x + pcomb[2][r][o0]);
            pv.y = m0 * (acc[0][r].y + pcomb[0][r][o0 + 1])
                 + m1 * (acc[1][r].y + pcomb[1][r][o0 + 1])
                 + m2 * (acc[2][r].y + pcomb[2][r][o0 + 1]);
            *(float2*)&part[((size_t)sl * kBN + row) * kFOUT + o0] = pv;
        }
    }
}

// ---------------------------------------------------------------------------
// Kernel 1b: reduce k-slice partials -> h (+ mask-weighted bias), s1/s2,
// emb.a2 table. Grid 512 x 256 threads, 8 rows/block.
// ---------------------------------------------------------------------------
__global__ __launch_bounds__(256) void reduce_kernel(
    const float* __restrict__ part,      // (4, B*N, FOUT)
    const float* __restrict__ mask,      // (T, B*N)
    const float* __restrict__ bias,      // (T, FOUT)
    const float* __restrict__ a1,
    const float* __restrict__ a2,
    const float* __restrict__ a_b,
    const float* __restrict__ emb,       // (NE+1, FOUT)
    float* __restrict__ h,               // (B*N, FOUT)
    float* __restrict__ s1,              // (B*N) a_b folded
    float* __restrict__ s2,              // (B*N)
    float* __restrict__ emb_a2)          // (16)
{
    __shared__ float hls[8][kFOUT];      // 4 KB

    const int tid  = threadIdx.x;
    const int row0 = blockIdx.x * 8;
    const int o    = tid & 127;
    const int rh   = tid >> 7;           // 0..1 -> 4 rows each

    #pragma unroll
    for (int rr = 0; rr < 4; ++rr) {
        const int r   = rh * 4 + rr;
        const int row = row0 + r;
        float hv = part[((size_t)0 * kBN + row) * kFOUT + o]
                 + part[((size_t)1 * kBN + row) * kFOUT + o]
                 + part[((size_t)2 * kBN + row) * kFOUT + o]
                 + part[((size_t)3 * kBN + row) * kFOUT + o];
        hv += mask[0 * kBN + row] * bias[0 * kFOUT + o]
            + mask[1 * kBN + row] * bias[1 * kFOUT + o]
            + mask[2 * kBN + row] * bias[2 * kFOUT + o];
        h[(size_t)row * kFOUT + o] = hv;
        hls[r][o] = hv;
    }
    __syncthreads();

    // s1/s2: 4 waves x 2 rows
    {
        const int wv = tid >> 6, lane = tid & 63;
        #pragma unroll
        for (int rr = 0; rr < 2; ++rr) {
            const int r = wv * 2 + rr;
            const float v0 = hls[r][lane];
            const float v1 = hls[r][64 + lane];
            float p1 = v0 * a1[lane] + v1 * a1[64 + lane];
            float p2 = v0 * a2[lane] + v1 * a2[64 + lane];
            #pragma unroll
            for (int off = 32; off; off >>= 1) {
                p1 += __shfl_down(p1, off);
                p2 += __shfl_down(p2, off);
            }
            if (lane == 0) {
                s1[row0 + r] = p1 + a_b[0];
                s2[row0 + r] = p2;
            }
        }
    }

    // emb.a2 table once (block 0): 11 rows x 16 lanes
    if (blockIdx.x == 0 && tid < 176) {
        const int e = tid >> 4, l = tid & 15;
        float p = 0.f;
        #pragma unroll
        for (int k8 = 0; k8 < 8; ++k8)
            p += emb[e * kFOUT + l + k8 * 16] * a2[l + k8 * 16];
        #pragma unroll
        for (int off = 8; off; off >>= 1) p += __shfl_xor(p, off);
        if (l == 0) emb_a2[e] = p;
    }
}

// ---------------------------------------------------------------------------
// Kernel 2: scores + softmax + histogram + dense attn@h + ELU.
// Same algorithm as round 7/8 but 512 threads (16 waves/CU): Phase C thread
// = (f4l:32, rg:2 -> 4 rows, js:8 -> 64-j slice); 8 j-partials combined via
// dead adjs (slots 0-3) + dead sc (slots 4-7). ~49 KB LDS, 2 blocks/CU.
// ---------------------------------------------------------------------------
__global__ __launch_bounds__(512) void attn_kernel(
    const int*   __restrict__ adj,     // (B, N, N)
    const float* __restrict__ emb,     // (NE+1, FOUT)
    const float* __restrict__ h,       // (B*N, FOUT)
    const float* __restrict__ s1,      // (B*N) a_b folded
    const float* __restrict__ s2,      // (B*N)
    const float* __restrict__ emb_a2g, // (16)
    float* __restrict__ out)           // (B*N, FOUT)
{
    __shared__ float sc[8][kN + 4];    // 16.5 KB raw scores (reused: parts 4-7)
    __shared__ int   adjs[8][kN];      // 16 KB (reused: parts 0-3)
    __shared__ float scT[kN][8];       // 16 KB transposed attn
    __shared__ float wsum[8][16];
    __shared__ float ea2[16];

    const int tid = threadIdx.x;
    const int b   = blockIdx.x >> 6;
    const int i0  = (blockIdx.x & 63) * 8;

    if (tid < 16) ea2[tid] = emb_a2g[tid];
    __syncthreads();

    // Phase A: scores, 1024 quads over 512 threads
    const int*   adjb = adj + ((size_t)(b * kN + i0)) * kN;
    const float* s2b  = s2 + b * kN;
    #pragma unroll
    for (int it = 0; it < 2; ++it) {
        const int idx = tid + it * 512;      // < 1024
        const int r = idx >> 7, jq = idx & 127;
        const int4   av  = *(const int4*)&adjb[(size_t)r * kN + jq * 4];
        const float4 s2v = *(const float4*)&s2b[jq * 4];
        const float  sr  = s1[b * kN + i0 + r];
        float4 sv; float s;
        s = sr + s2v.x + ea2[av.x]; s = s > 0.f ? s : kALPHA * s; sv.x = av.x > 0 ? s : kNEG;
        s = sr + s2v.y + ea2[av.y]; s = s > 0.f ? s : kALPHA * s; sv.y = av.y > 0 ? s : kNEG;
        s = sr + s2v.z + ea2[av.z]; s = s > 0.f ? s : kALPHA * s; sv.z = av.z > 0 ? s : kNEG;
        s = sr + s2v.w + ea2[av.w]; s = s > 0.f ? s : kALPHA * s; sv.w = av.w > 0 ? s : kNEG;
        *(float4*)&sc[r][jq * 4] = sv;
        *(int4*)&adjs[r][jq * 4] = av;
    }
    __syncthreads();

    // Phase B: softmax + histogram, wave per row (8 waves = 8 rows)
    {
        const int r = tid >> 6, lane = tid & 63;
        float v[8]; int av[8];
        #pragma unroll
        for (int k = 0; k < 8; ++k) {
            v[k]  = sc[r][lane + k * 64];
            av[k] = adjs[r][lane + k * 64];
        }
        float m = v[0];
        #pragma unroll
        for (int k = 1; k < 8; ++k) m = fmaxf(m, v[k]);
        #pragma unroll
        for (int off = 32; off; off >>= 1) m = fmaxf(m, __shfl_xor(m, off));
        float sum = 0.f;
        #pragma unroll
        for (int k = 0; k < 8; ++k) { v[k] = __expf(v[k] - m); sum += v[k]; }
        #pragma unroll
        for (int off = 32; off; off >>= 1) sum += __shfl_xor(sum, off);
        const float inv = 1.0f / sum;
        #pragma unroll
        for (int k = 0; k < 8; ++k) {
            v[k] *= inv;
            scT[lane + k * 64][r] = v[k];
        }
        #pragma unroll
        for (int e = 1; e <= kNE; ++e) {
            float p = 0.f;
            #pragma unroll
            for (int k = 0; k < 8; ++k) p += (av[k] == e) ? v[k] : 0.f;
            #pragma unroll
            for (int off = 32; off; off >>= 1) p += __shfl_xor(p, off);
            if (lane == 0) wsum[r][e] = p;
        }
    }
    __syncthreads();

    // Phase C: dense attn @ h. thread = (f4l:32, rg:2 -> 4 rows, js:8 slices)
    const int f4l = tid & 31;
    const int rg  = (tid >> 5) & 1;
    const int js  = tid >> 6;              // 0..7, 64 j each
    const float* hb  = h + ((size_t)(b * kN + js * 64)) * kFOUT + f4l * 4;
    const float* sct = &scT[js * 64][rg * 4];

    float4 acc0 = {0,0,0,0}, acc1 = {0,0,0,0}, acc2 = {0,0,0,0}, acc3 = {0,0,0,0};
    #pragma unroll 4
    for (int jj = 0; jj < 64; ++jj) {
        const float4 w4 = *(const float4*)&sct[jj * 8];   // LDS b128 broadcast
        const float4 hv = *(const float4*)&hb[(size_t)jj * kFOUT];
        acc0.x = fmaf(w4.x, hv.x, acc0.x); acc0.y = fmaf(w4.x, hv.y, acc0.y);
        acc0.z = fmaf(w4.x, hv.z, acc0.z); acc0.w = fmaf(w4.x, hv.w, acc0.w);
        acc1.x = fmaf(w4.y, hv.x, acc1.x); acc1.y = fmaf(w4.y, hv.y, acc1.y);
        acc1.z = fmaf(w4.y, hv.z, acc1.z); acc1.w = fmaf(w4.y, hv.w, acc1.w);
        acc2.x = fmaf(w4.z, hv.x, acc2.x); acc2.y = fmaf(w4.z, hv.y, acc2.y);
        acc2.z = fmaf(w4.z, hv.z, acc2.z); acc2.w = fmaf(w4.z, hv.w, acc2.w);
        acc3.x = fmaf(w4.w, hv.x, acc3.x); acc3.y = fmaf(w4.w, hv.y, acc3.y);
        acc3.z = fmaf(w4.w, hv.z, acc3.z); acc3.w = fmaf(w4.w, hv.w, acc3.w);
    }
    __syncthreads();                       // sc & adjs dead -> reuse as parts

    float* parts_lo = (float*)adjs;        // slots 0-3: [js][8 r][128 f]
    float* parts_hi = (float*)sc;          // slots 4-7 (first 4096 floats)
    {
        float* pbase = (js < 4) ? parts_lo + js * 1024
                                : parts_hi + (js - 4) * 1024;
        const int rbase = rg * 4;
        *(float4*)&pbase[(rbase + 0) * kFOUT + f4l * 4] = acc0;
        *(float4*)&pbase[(rbase + 1) * kFOUT + f4l * 4] = acc1;
        *(float4*)&pbase[(rbase + 2) * kFOUT + f4l * 4] = acc2;
        *(float4*)&pbase[(rbase + 3) * kFOUT + f4l * 4] = acc3;
    }
    __syncthreads();

    // Reduction + emb correction + ELU + store (256 active threads)
    if (tid < 256) {
        const int r  = tid >> 5;
        const int fl = (tid & 31) * 4;
        float4 a = {0,0,0,0};
        #pragma unroll
        for (int p = 0; p < 4; ++p) {
            const float4 v0 = *(const float4*)&parts_lo[p * 1024 + r * kFOUT + fl];
            const float4 v1 = *(const float4*)&parts_hi[p * 1024 + r * kFOUT + fl];
            a.x += v0.x + v1.x; a.y += v0.y + v1.y;
            a.z += v0.z + v1.z; a.w += v0.w + v1.w;
        }
        #pragma unroll
        for (int e = 1; e <= kNE; ++e) {
            const float  wv = wsum[r][e];
            const float4 ev = *(const float4*)&emb[e * kFOUT + fl];
            a.x = fmaf(wv, ev.x, a.x); a.y = fmaf(wv, ev.y, a.y);
            a.z = fmaf(wv, ev.z, a.z); a.w = fmaf(wv, ev.w, a.w);
        }
        a.x = a.x > 0.f ? a.x : expm1f(a.x);
        a.y = a.y > 0.f ? a.y : expm1f(a.y);
        a.z = a.z > 0.f ? a.z : expm1f(a.z);
        a.w = a.w > 0.f ? a.w : expm1f(a.w);
        *(float4*)&out[((size_t)(b * kN + i0 + r)) * kFOUT + fl] = a;
    }
}

// ---------------------------------------------------------------------------
extern "C" void kernel_launch(void* const* d_in, const int* in_sizes, int n_in,
                              void* d_out, int out_size, void* d_ws, size_t ws_size,
                              hipStream_t stream) {
    const float* node_rep = (const float*)d_in[0];
    const float* mask     = (const float*)d_in[1];
    const int*   adj      = (const int*)  d_in[2];
    const float* W        = (const float*)d_in[3];
    const float* bias     = (const float*)d_in[4];
    const float* a1       = (const float*)d_in[5];
    const float* a2       = (const float*)d_in[6];
    const float* a_b      = (const float*)d_in[7];
    const float* emb      = (const float*)d_in[8];
    float* out = (float*)d_out;

    float* ws     = (float*)d_ws;
    float* h      = ws;                            // B*N*FOUT (2 MB)
    float* s1     = h + (size_t)kBN * kFOUT;       // B*N
    float* s2     = s1 + kBN;                      // B*N
    float* emb_a2 = s2 + kBN;                      // 16
    float* part   = emb_a2 + 16;                   // 4 * B*N * FOUT (8 MB)

    proj_kernel<<<2048, 128, 0, stream>>>(node_rep, mask, W, part);
    reduce_kernel<<<kBN / 8, 256, 0, stream>>>(
        part, mask, bias, a1, a2, a_b, emb, h, s1, s2, emb_a2);
    attn_kernel<<<kBN / 8, 512, 0, stream>>>(
        adj, emb, h, s1, s2, emb_a2, out);
}

// Round 10
// 108.745 us; speedup vs baseline: 1.0513x; 1.0259x over previous
//
#include <hip/hip_runtime.h>

constexpr int kB    = 8;
constexpr int kN    = 512;
constexpr int kFIN  = 256;
constexpr int kFOUT = 128;
constexpr int kNE   = 10;
constexpr int kBN   = kB * kN;
constexpr float kALPHA = 0.2f;
constexpr float kNEG   = -9e15f;

typedef __attribute__((ext_vector_type(8))) short bhalf8;
typedef __attribute__((ext_vector_type(4))) float f32x4;

__device__ __forceinline__ unsigned short bf16_trunc(float x) {
    union { float f; unsigned u; } c; c.f = x;
    return (unsigned short)(c.u >> 16);
}
__device__ __forceinline__ float bf16_tof(unsigned short h) {
    union { unsigned u; float f; } c; c.u = ((unsigned)h) << 16;
    return c.f;
}

// ---------------------------------------------------------------------------
// Kernel 0: prep — split X into bf16 hi/lo (row-major, so MFMA A-fragments
// are 16B-contiguous per lane) and pack W into B-fragment order:
//   Wpack[((t*8+ks)*8+nt)*512 + lane*8 + j] = W[t][ks*32+(lane>>4)*8+j][nt*16+(lane&15)]
// Blocks 0..1023: X (4 floats/thread). Blocks 1024..1071: Wpack.
// ---------------------------------------------------------------------------
__global__ __launch_bounds__(256) void prep_kernel(
    const float* __restrict__ node_rep,   // (B*N, FIN)
    const float* __restrict__ W,          // (T, FIN, FOUT)
    unsigned short* __restrict__ Xh,      // (B*N * FIN)
    unsigned short* __restrict__ Xl,
    unsigned short* __restrict__ Whp,     // (3*8*8*512)
    unsigned short* __restrict__ Wlp)
{
    const int tid = threadIdx.x;
    if (blockIdx.x < 1024) {
        const int gid  = blockIdx.x * 256 + tid;     // < 262144
        const size_t base = (size_t)gid * 4;
        const float4 v = *(const float4*)&node_rep[base];
        ushort4 hi, lo;
        float t;
        hi.x = bf16_trunc(v.x); t = v.x - bf16_tof(hi.x); lo.x = bf16_trunc(t);
        hi.y = bf16_trunc(v.y); t = v.y - bf16_tof(hi.y); lo.y = bf16_trunc(t);
        hi.z = bf16_trunc(v.z); t = v.z - bf16_tof(hi.z); lo.z = bf16_trunc(t);
        hi.w = bf16_trunc(v.w); t = v.w - bf16_tof(hi.w); lo.w = bf16_trunc(t);
        *(ushort4*)&Xh[base] = hi;
        *(ushort4*)&Xl[base] = lo;
    } else {
        const int g    = (blockIdx.x - 1024) * 256 + tid;  // < 12288
        const int lane = g & 63;
        const int nt   = (g >> 6) & 7;
        const int ks   = (g >> 9) & 7;
        const int tt   = g >> 12;                           // 0..2
        const int col  = nt * 16 + (lane & 15);
        const int kb   = ks * 32 + ((lane >> 4) * 8);
        unsigned short hbuf[8], lbuf[8];
        #pragma unroll
        for (int j = 0; j < 8; ++j) {
            const float w = W[((size_t)tt * kFIN + kb + j) * kFOUT + col];
            hbuf[j] = bf16_trunc(w);
            lbuf[j] = bf16_trunc(w - bf16_tof(hbuf[j]));
        }
        const size_t dst = ((size_t)((tt * 8 + ks) * 8 + nt)) * 512 + lane * 8;
        #pragma unroll
        for (int j = 0; j < 8; ++j) { Whp[dst + j] = hbuf[j]; Wlp[dst + j] = lbuf[j]; }
    }
}

// ---------------------------------------------------------------------------
// Kernel 1: typed projection via split-bf16 MFMA.
//   Y_t = Xh@Wh + Xh@Wl + Xl@Wh  (f32 accum; dropped lo*lo term ~2^-16 rel)
// Grid 384 = 128 row-blocks x 3 types. Block 256 thr = 4 waves.
// Wave (wrow = w&1, whalf = w>>1): rows [rb*32+wrow*16, +16), cols
// [whalf*64, +64) as 4 N-tiles of 16. K-loop: 8 steps of 32.
// A-frag: lane l holds X[row0 + (l&15)][k0 + (l>>4)*8 + j]  (16B contiguous)
// B-frag: from Wpack (pre-swizzled, 16B contiguous per lane)
// C/D (m89-verified): reg j of lane l = Y[(l>>4)*4 + j][l&15] within tile.
// 96 MFMA/wave.
// ---------------------------------------------------------------------------
__global__ __launch_bounds__(256) void proj_mfma_kernel(
    const unsigned short* __restrict__ Xh,
    const unsigned short* __restrict__ Xl,
    const unsigned short* __restrict__ Whp,
    const unsigned short* __restrict__ Wlp,
    float* __restrict__ y)                // (3, B*N, FOUT)
{
    const int tid   = threadIdx.x;
    const int t     = blockIdx.x % 3;
    const int rb    = blockIdx.x / 3;     // 0..127
    const int wave  = tid >> 6;
    const int lane  = tid & 63;
    const int wrow  = wave & 1;
    const int whalf = wave >> 1;

    const int rowA = rb * 32 + wrow * 16 + (lane & 15);
    const unsigned short* xhp = Xh + (size_t)rowA * kFIN + ((lane >> 4) * 8);
    const unsigned short* xlp = Xl + (size_t)rowA * kFIN + ((lane >> 4) * 8);

    f32x4 acc[4] = {{0,0,0,0},{0,0,0,0},{0,0,0,0},{0,0,0,0}};

    #pragma unroll
    for (int ks = 0; ks < 8; ++ks) {
        const bhalf8 Ah = *(const bhalf8*)(xhp + ks * 32);
        const bhalf8 Al = *(const bhalf8*)(xlp + ks * 32);
        const size_t bw = ((size_t)((t * 8 + ks) * 8 + whalf * 4)) * 512 + lane * 8;
        #pragma unroll
        for (int n = 0; n < 4; ++n) {
            const bhalf8 Bh = *(const bhalf8*)(Whp + bw + n * 512);
            const bhalf8 Bl = *(const bhalf8*)(Wlp + bw + n * 512);
            acc[n] = __builtin_amdgcn_mfma_f32_16x16x32_bf16(Ah, Bh, acc[n], 0, 0, 0);
            acc[n] = __builtin_amdgcn_mfma_f32_16x16x32_bf16(Ah, Bl, acc[n], 0, 0, 0);
            acc[n] = __builtin_amdgcn_mfma_f32_16x16x32_bf16(Al, Bh, acc[n], 0, 0, 0);
        }
    }

    const int rbase = rb * 32 + wrow * 16 + ((lane >> 4) * 4);
    const int cbase = whalf * 64 + (lane & 15);
    #pragma unroll
    for (int n = 0; n < 4; ++n)
        #pragma unroll
        for (int j = 0; j < 4; ++j)
            y[((size_t)t * kBN + rbase + j) * kFOUT + cbase + n * 16] = acc[n][j];
}

// ---------------------------------------------------------------------------
// Kernel 2: reduce y_t -> h = sum_t m_t*(y_t + b_t); s1/s2; emb.a2 table.
// ---------------------------------------------------------------------------
__global__ __launch_bounds__(256) void reduce_kernel(
    const float* __restrict__ y,         // (3, B*N, FOUT)
    const float* __restrict__ mask,      // (T, B*N)
    const float* __restrict__ bias,      // (T, FOUT)
    const float* __restrict__ a1,
    const float* __restrict__ a2,
    const float* __restrict__ a_b,
    const float* __restrict__ emb,       // (NE+1, FOUT)
    float* __restrict__ h,               // (B*N, FOUT)
    float* __restrict__ s1,              // (B*N) a_b folded
    float* __restrict__ s2,              // (B*N)
    float* __restrict__ emb_a2)          // (16)
{
    __shared__ float hls[8][kFOUT];      // 4 KB

    const int tid  = threadIdx.x;
    const int row0 = blockIdx.x * 8;
    const int o    = tid & 127;
    const int rh   = tid >> 7;           // 0..1 -> 4 rows each

    #pragma unroll
    for (int rr = 0; rr < 4; ++rr) {
        const int r   = rh * 4 + rr;
        const int row = row0 + r;
        const float hv =
              mask[0 * kBN + row] * (y[((size_t)0 * kBN + row) * kFOUT + o] + bias[0 * kFOUT + o])
            + mask[1 * kBN + row] * (y[((size_t)1 * kBN + row) * kFOUT + o] + bias[1 * kFOUT + o])
            + mask[2 * kBN + row] * (y[((size_t)2 * kBN + row) * kFOUT + o] + bias[2 * kFOUT + o]);
        h[(size_t)row * kFOUT + o] = hv;
        hls[r][o] = hv;
    }
    __syncthreads();

    {   // s1/s2: 4 waves x 2 rows
        const int wv = tid >> 6, lane = tid & 63;
        #pragma unroll
        for (int rr = 0; rr < 2; ++rr) {
            const int r = wv * 2 + rr;
            const float v0 = hls[r][lane];
            const float v1 = hls[r][64 + lane];
            float p1 = v0 * a1[lane] + v1 * a1[64 + lane];
            float p2 = v0 * a2[lane] + v1 * a2[64 + lane];
            #pragma unroll
            for (int off = 32; off; off >>= 1) {
                p1 += __shfl_down(p1, off);
                p2 += __shfl_down(p2, off);
            }
            if (lane == 0) {
                s1[row0 + r] = p1 + a_b[0];
                s2[row0 + r] = p2;
            }
        }
    }

    if (blockIdx.x == 0 && tid < 176) {  // emb.a2 table
        const int e = tid >> 4, l = tid & 15;
        float p = 0.f;
        #pragma unroll
        for (int k8 = 0; k8 < 8; ++k8)
            p += emb[e * kFOUT + l + k8 * 16] * a2[l + k8 * 16];
        #pragma unroll
        for (int off = 8; off; off >>= 1) p += __shfl_xor(p, off);
        if (l == 0) emb_a2[e] = p;
    }
}

// ---------------------------------------------------------------------------
// Kernel 3: scores + softmax + histogram + dense attn@h + ELU.
// (UNCHANGED from round 9.)
// ---------------------------------------------------------------------------
__global__ __launch_bounds__(512) void attn_kernel(
    const int*   __restrict__ adj,     // (B, N, N)
    const float* __restrict__ emb,     // (NE+1, FOUT)
    const float* __restrict__ h,       // (B*N, FOUT)
    const float* __restrict__ s1,      // (B*N) a_b folded
    const float* __restrict__ s2,      // (B*N)
    const float* __restrict__ emb_a2g, // (16)
    float* __restrict__ out)           // (B*N, FOUT)
{
    __shared__ float sc[8][kN + 4];
    __shared__ int   adjs[8][kN];
    __shared__ float scT[kN][8];
    __shared__ float wsum[8][16];
    __shared__ float ea2[16];

    const int tid = threadIdx.x;
    const int b   = blockIdx.x >> 6;
    const int i0  = (blockIdx.x & 63) * 8;

    if (tid < 16) ea2[tid] = emb_a2g[tid];
    __syncthreads();

    const int*   adjb = adj + ((size_t)(b * kN + i0)) * kN;
    const float* s2b  = s2 + b * kN;
    #pragma unroll
    for (int it = 0; it < 2; ++it) {
        const int idx = tid + it * 512;
        const int r = idx >> 7, jq = idx & 127;
        const int4   av  = *(const int4*)&adjb[(size_t)r * kN + jq * 4];
        const float4 s2v = *(const float4*)&s2b[jq * 4];
        const float  sr  = s1[b * kN + i0 + r];
        float4 sv; float s;
        s = sr + s2v.x + ea2[av.x]; s = s > 0.f ? s : kALPHA * s; sv.x = av.x > 0 ? s : kNEG;
        s = sr + s2v.y + ea2[av.y]; s = s > 0.f ? s : kALPHA * s; sv.y = av.y > 0 ? s : kNEG;
        s = sr + s2v.z + ea2[av.z]; s = s > 0.f ? s : kALPHA * s; sv.z = av.z > 0 ? s : kNEG;
        s = sr + s2v.w + ea2[av.w]; s = s > 0.f ? s : kALPHA * s; sv.w = av.w > 0 ? s : kNEG;
        *(float4*)&sc[r][jq * 4] = sv;
        *(int4*)&adjs[r][jq * 4] = av;
    }
    __syncthreads();

    {
        const int r = tid >> 6, lane = tid & 63;
        float v[8]; int av[8];
        #pragma unroll
        for (int k = 0; k < 8; ++k) {
            v[k]  = sc[r][lane + k * 64];
            av[k] = adjs[r][lane + k * 64];
        }
        float m = v[0];
        #pragma unroll
        for (int k = 1; k < 8; ++k) m = fmaxf(m, v[k]);
        #pragma unroll
        for (int off = 32; off; off >>= 1) m = fmaxf(m, __shfl_xor(m, off));
        float sum = 0.f;
        #pragma unroll
        for (int k = 0; k < 8; ++k) { v[k] = __expf(v[k] - m); sum += v[k]; }
        #pragma unroll
        for (int off = 32; off; off >>= 1) sum += __shfl_xor(sum, off);
        const float inv = 1.0f / sum;
        #pragma unroll
        for (int k = 0; k < 8; ++k) {
            v[k] *= inv;
            scT[lane + k * 64][r] = v[k];
        }
        #pragma unroll
        for (int e = 1; e <= kNE; ++e) {
            float p = 0.f;
            #pragma unroll
            for (int k = 0; k < 8; ++k) p += (av[k] == e) ? v[k] : 0.f;
            #pragma unroll
            for (int off = 32; off; off >>= 1) p += __shfl_xor(p, off);
            if (lane == 0) wsum[r][e] = p;
        }
    }
    __syncthreads();

    const int f4l = tid & 31;
    const int rg  = (tid >> 5) & 1;
    const int js  = tid >> 6;
    const float* hb  = h + ((size_t)(b * kN + js * 64)) * kFOUT + f4l * 4;
    const float* sct = &scT[js * 64][rg * 4];

    float4 acc0 = {0,0,0,0}, acc1 = {0,0,0,0}, acc2 = {0,0,0,0}, acc3 = {0,0,0,0};
    #pragma unroll 4
    for (int jj = 0; jj < 64; ++jj) {
        const float4 w4 = *(const float4*)&sct[jj * 8];
        const float4 hv = *(const float4*)&hb[(size_t)jj * kFOUT];
        acc0.x = fmaf(w4.x, hv.x, acc0.x); acc0.y = fmaf(w4.x, hv.y, acc0.y);
        acc0.z = fmaf(w4.x, hv.z, acc0.z); acc0.w = fmaf(w4.x, hv.w, acc0.w);
        acc1.x = fmaf(w4.y, hv.x, acc1.x); acc1.y = fmaf(w4.y, hv.y, acc1.y);
        acc1.z = fmaf(w4.y, hv.z, acc1.z); acc1.w = fmaf(w4.y, hv.w, acc1.w);
        acc2.x = fmaf(w4.z, hv.x, acc2.x); acc2.y = fmaf(w4.z, hv.y, acc2.y);
        acc2.z = fmaf(w4.z, hv.z, acc2.z); acc2.w = fmaf(w4.z, hv.w, acc2.w);
        acc3.x = fmaf(w4.w, hv.x, acc3.x); acc3.y = fmaf(w4.w, hv.y, acc3.y);
        acc3.z = fmaf(w4.w, hv.z, acc3.z); acc3.w = fmaf(w4.w, hv.w, acc3.w);
    }
    __syncthreads();

    float* parts_lo = (float*)adjs;
    float* parts_hi = (float*)sc;
    {
        float* pbase = (js < 4) ? parts_lo + js * 1024
                                : parts_hi + (js - 4) * 1024;
        const int rbase = rg * 4;
        *(float4*)&pbase[(rbase + 0) * kFOUT + f4l * 4] = acc0;
        *(float4*)&pbase[(rbase + 1) * kFOUT + f4l * 4] = acc1;
        *(float4*)&pbase[(rbase + 2) * kFOUT + f4l * 4] = acc2;
        *(float4*)&pbase[(rbase + 3) * kFOUT + f4l * 4] = acc3;
    }
    __syncthreads();

    if (tid < 256) {
        const int r  = tid >> 5;
        const int fl = (tid & 31) * 4;
        float4 a = {0,0,0,0};
        #pragma unroll
        for (int p = 0; p < 4; ++p) {
            const float4 v0 = *(const float4*)&parts_lo[p * 1024 + r * kFOUT + fl];
            const float4 v1 = *(const float4*)&parts_hi[p * 1024 + r * kFOUT + fl];
            a.x += v0.x + v1.x; a.y += v0.y + v1.y;
            a.z += v0.z + v1.z; a.w += v0.w + v1.w;
        }
        #pragma unroll
        for (int e = 1; e <= kNE; ++e) {
            const float  wv = wsum[r][e];
            const float4 ev = *(const float4*)&emb[e * kFOUT + fl];
            a.x = fmaf(wv, ev.x, a.x); a.y = fmaf(wv, ev.y, a.y);
            a.z = fmaf(wv, ev.z, a.z); a.w = fmaf(wv, ev.w, a.w);
        }
        a.x = a.x > 0.f ? a.x : expm1f(a.x);
        a.y = a.y > 0.f ? a.y : expm1f(a.y);
        a.z = a.z > 0.f ? a.z : expm1f(a.z);
        a.w = a.w > 0.f ? a.w : expm1f(a.w);
        *(float4*)&out[((size_t)(b * kN + i0 + r)) * kFOUT + fl] = a;
    }
}

// ---------------------------------------------------------------------------
extern "C" void kernel_launch(void* const* d_in, const int* in_sizes, int n_in,
                              void* d_out, int out_size, void* d_ws, size_t ws_size,
                              hipStream_t stream) {
    const float* node_rep = (const float*)d_in[0];
    const float* mask     = (const float*)d_in[1];
    const int*   adj      = (const int*)  d_in[2];
    const float* W        = (const float*)d_in[3];
    const float* bias     = (const float*)d_in[4];
    const float* a1       = (const float*)d_in[5];
    const float* a2       = (const float*)d_in[6];
    const float* a_b      = (const float*)d_in[7];
    const float* emb      = (const float*)d_in[8];
    float* out = (float*)d_out;

    float* fws    = (float*)d_ws;
    float* h      = fws;                           // 524288 f (2 MB)
    float* s1     = h + (size_t)kBN * kFOUT;       // 4096
    float* s2     = s1 + kBN;                      // 4096
    float* emb_a2 = s2 + kBN;                      // 64 (padded)
    float* y      = emb_a2 + 64;                   // 3*524288 f (6 MB)
    unsigned short* Xh  = (unsigned short*)(y + (size_t)3 * kBN * kFOUT);
    unsigned short* Xl  = Xh + (size_t)kBN * kFIN; // 1048576 ea
    unsigned short* Whp = Xl + (size_t)kBN * kFIN;
    unsigned short* Wlp = Whp + 3 * 8 * 8 * 512;   // 98304 ea

    prep_kernel<<<1072, 256, 0, stream>>>(node_rep, W, Xh, Xl, Whp, Wlp);
    proj_mfma_kernel<<<384, 256, 0, stream>>>(Xh, Xl, Whp, Wlp, y);
    reduce_kernel<<<kBN / 8, 256, 0, stream>>>(
        y, mask, bias, a1, a2, a_b, emb, h, s1, s2, emb_a2);
    attn_kernel<<<kBN / 8, 512, 0, stream>>>(
        adj, emb, h, s1, s2, emb_a2, out);
}